// Round 17
// baseline (239.595 us; speedup 1.0000x reference)
//
#include <hip/hip_runtime.h>
#include <hip/hip_bf16.h>

#define N_NODES 50000
#define N_EDGES 800000
#define D_FEAT  64
#define SCAN_B  256
#define SCAN_NBLK ((N_NODES + SCAN_B - 1) / SCAN_B)   // 196
#define NB      12800    // LDS bins per range (50 KB)
#define RANGES  4        // ceil(50000/12800)
#define G_STR   64       // edge stripes
#define NPP     50000
#define HB      512      // hist/scatter block size (8 waves)

// ---------------- bf16 helpers ----------------
__device__ __forceinline__ float bflo(unsigned u) { return __uint_as_float(u << 16); }
__device__ __forceinline__ float bfhi(unsigned u) { return __uint_as_float(u & 0xFFFF0000u); }
__device__ __forceinline__ unsigned pack_bf16(float a, float b) {
    __hip_bfloat16 x = __float2bfloat16(a), y = __float2bfloat16(b);
    unsigned short ux = *reinterpret_cast<unsigned short*>(&x);
    unsigned short uy = *reinterpret_cast<unsigned short*>(&y);
    return (unsigned)ux | ((unsigned)uy << 16);
}

// ---------------- build kernels (no global atomics) ----------------

// grid (G_STR, RANGES, 3). z=0: src hist; z=1: dst hist; z=2: feat->bf16 convert.
__global__ void hist_cv_kernel(const int* __restrict__ src, const int* __restrict__ dst,
                               int* __restrict__ psrc, int* __restrict__ pdst,
                               const float* __restrict__ feat, unsigned* __restrict__ featbf,
                               int nE) {
    int type = blockIdx.z;
    int t = threadIdx.x;
    if (type == 2) {
        int cb = blockIdx.x * RANGES + blockIdx.y;   // 0..255
        const float4* f4 = (const float4*)feat;
        for (int i = cb * HB + t; i < N_NODES * 16; i += 256 * HB) {
            float4 v = f4[i];
            featbf[2 * i]     = pack_bf16(v.x, v.y);
            featbf[2 * i + 1] = pack_bf16(v.z, v.w);
        }
        return;
    }
    __shared__ int bins[NB];
    for (int i = t; i < NB; i += HB) bins[i] = 0;
    __syncthreads();
    int g = blockIdx.x, range = blockIdx.y;
    const int* keys = (type == 0) ? src : dst;
    int lo = range * NB;
    for (int e = g * HB + t; e < nE; e += G_STR * HB) {
        unsigned k = (unsigned)(keys[e] - lo);
        if (k < NB) atomicAdd(&bins[k], 1);       // LDS atomic
    }
    __syncthreads();
    int* p = ((type == 0) ? psrc : pdst) + g * NPP;
    for (int i = t; i < NB; i += HB) {
        int node = lo + i;
        if (node < N_NODES) p[node] = bins[i];
    }
}

// Phase A: per-node totals -> tot; block sums -> partials; fused dinv
__global__ void scanA_kernel(const int* __restrict__ pdst, const int* __restrict__ psrc,
                             int* __restrict__ tot, int* __restrict__ partials,
                             float* __restrict__ dinv, int n) {
    __shared__ int red[SCAN_B];
    int t = threadIdx.x;
    int idx = blockIdx.x * SCAN_B + t;
    int v = 0;
    if (idx < n) {
        int cs = 0;
        #pragma unroll 16
        for (int g = 0; g < G_STR; g++) {
            v  += pdst[g * NPP + idx];
            cs += psrc[g * NPP + idx];
        }
        tot[idx] = v;
        dinv[idx] = (cs > 0) ? rsqrtf((float)cs) : 0.0f;
    }
    red[t] = v;
    __syncthreads();
    for (int off = SCAN_B / 2; off > 0; off >>= 1) {
        if (t < off) red[t] += red[t + off];
        __syncthreads();
    }
    if (t == 0) partials[blockIdx.x] = red[0];
}

// Phase C (scanB folded in): every block scans the 196 partials in LDS for its
// own base, then does the per-node exclusive scan -> offs and gbase.
__global__ void scanC_kernel(const int* __restrict__ tot, const int* __restrict__ pdst,
                             const int* __restrict__ partials,
                             int* __restrict__ offs, int* __restrict__ gbase, int n) {
    __shared__ int sp[SCAN_B];
    __shared__ int sn[SCAN_B];
    int t = threadIdx.x;
    int b = blockIdx.x;
    sp[t] = (t < SCAN_NBLK) ? partials[t] : 0;
    __syncthreads();
    for (int off = 1; off < SCAN_B; off <<= 1) {
        int u = (t >= off) ? sp[t - off] : 0;
        __syncthreads();
        sp[t] += u;
        __syncthreads();
    }
    int base = (b == 0) ? 0 : sp[b - 1];
    if (b == SCAN_NBLK - 1 && t == 0) offs[n] = sp[SCAN_NBLK - 1];
    int idx = b * SCAN_B + t;
    int v = (idx < n) ? tot[idx] : 0;
    sn[t] = v;
    __syncthreads();
    for (int off = 1; off < SCAN_B; off <<= 1) {
        int u = (t >= off) ? sn[t - off] : 0;
        __syncthreads();
        sn[t] += u;
        __syncthreads();
    }
    if (idx < n) {
        int off0 = base + sn[t] - v;   // exclusive
        offs[idx] = off0;
        int run = off0;
        #pragma unroll 16
        for (int g = 0; g < G_STR; g++) {
            gbase[g * NPP + idx] = run;
            run += pdst[g * NPP + idx];
        }
    }
}

// grid (G_STR, RANGES). Writes fused (src, dinv[src]) entries via LDS cursors.
__global__ void scatter_lds_kernel(const int* __restrict__ src, const int* __restrict__ dst,
                                   const int* __restrict__ gbase, const float* __restrict__ dinv,
                                   int2* __restrict__ csr2, int nE) {
    __shared__ int cur[NB];
    int t = threadIdx.x;
    int g = blockIdx.x, range = blockIdx.y;
    int lo = range * NB;
    for (int i = t; i < NB; i += HB) {
        int node = lo + i;
        cur[i] = (node < N_NODES) ? gbase[g * NPP + node] : 0;
    }
    __syncthreads();
    for (int e = g * HB + t; e < nE; e += G_STR * HB) {
        int d = dst[e];
        unsigned k = (unsigned)(d - lo);
        if (k < NB) {
            int pos = atomicAdd(&cur[k], 1);       // LDS atomic
            int s = src[e];
            csr2[pos] = make_int2(s, __float_as_int(dinv[s]));
        }
    }
}

// ---------------- gather SpMM (bf16 x, f32 accumulate) ----------------
// TWO waves per dst node (feature-split): half = gw&1 owns 32 features.
// Lanes: eg = lane>>2 (edge slot 0..15), c4 = lane&3 (16B col group within the
// half). 16 edges in flight per iteration -> avg deg-16 node = ONE iteration.
// Reduce over eg via shfl_xor 4/8/16/32; lanes 0..3 write.

struct Acc8 { float a0, a1, a2, a3, a4, a5, a6, a7; };

__device__ __forceinline__ Acc8 spmm_gather16(int i, int half, const int* __restrict__ offs,
                                              const int2* __restrict__ csr2,
                                              const unsigned* __restrict__ x,
                                              int eg, int c4) {
    int bg = offs[i], e2 = offs[i + 1];
    const uint4* x4 = (const uint4*)x;
    float a0 = 0, a1 = 0, a2 = 0, a3 = 0, a4 = 0, a5 = 0, a6 = 0, a7 = 0;
    int colIdx = half * 4 + c4;
    for (int j = bg; j < e2; j += 16) {
        int ej = j + eg;
        bool v = ej < e2;
        int2 sw = csr2[v ? ej : (e2 - 1)];
        float w = v ? __int_as_float(sw.y) : 0.0f;
        uint4 r = x4[(size_t)sw.x * 8 + colIdx];
        a0 += w * bflo(r.x); a1 += w * bfhi(r.x);
        a2 += w * bflo(r.y); a3 += w * bfhi(r.y);
        a4 += w * bflo(r.z); a5 += w * bfhi(r.z);
        a6 += w * bflo(r.w); a7 += w * bfhi(r.w);
    }
    #pragma unroll
    for (int d = 4; d <= 32; d <<= 1) {
        a0 += __shfl_xor(a0, d); a1 += __shfl_xor(a1, d);
        a2 += __shfl_xor(a2, d); a3 += __shfl_xor(a3, d);
        a4 += __shfl_xor(a4, d); a5 += __shfl_xor(a5, d);
        a6 += __shfl_xor(a6, d); a7 += __shfl_xor(a7, d);
    }
    Acc8 r = {a0, a1, a2, a3, a4, a5, a6, a7};
    return r;
}

// mid hop: y = A @ x  (bf16 out only)
__global__ void spmm_mid_kernel(const int* __restrict__ offs, const int2* __restrict__ csr2,
                                const float* __restrict__ dinv,
                                const unsigned* __restrict__ x, unsigned* __restrict__ y) {
    int gw = (blockIdx.x * blockDim.x + threadIdx.x) >> 6;
    int i = gw >> 1;
    int half = gw & 1;
    if (i >= N_NODES) return;
    int lane = threadIdx.x & 63;
    int eg = lane >> 2, c4 = lane & 3;
    Acc8 A = spmm_gather16(i, half, offs, csr2, x, eg, c4);
    if (lane < 4) {
        float di = dinv[i];
        uint4 p;
        p.x = pack_bf16(A.a0 * di, A.a1 * di);
        p.y = pack_bf16(A.a2 * di, A.a3 * di);
        p.z = pack_bf16(A.a4 * di, A.a5 * di);
        p.w = pack_bf16(A.a6 * di, A.a7 * di);
        ((uint4*)y)[(size_t)i * 8 + half * 4 + c4] = p;
    }
}

// final hop: x3 = A @ x2 ; h = 0.8*x1 + 0.15*x2 + 0.05*x3 (single h write)
__global__ void spmm_final_kernel(const int* __restrict__ offs, const int2* __restrict__ csr2,
                                  const float* __restrict__ dinv,
                                  const unsigned* __restrict__ x1, const unsigned* __restrict__ x2,
                                  float* __restrict__ h) {
    int gw = (blockIdx.x * blockDim.x + threadIdx.x) >> 6;
    int i = gw >> 1;
    int half = gw & 1;
    if (i >= N_NODES) return;
    int lane = threadIdx.x & 63;
    int eg = lane >> 2, c4 = lane & 3;
    Acc8 A = spmm_gather16(i, half, offs, csr2, x2, eg, c4);
    if (lane < 4) {
        float di = dinv[i] * 0.05f;
        size_t xidx = (size_t)i * 8 + half * 4 + c4;
        uint4 u1 = ((const uint4*)x1)[xidx];
        uint4 u2 = ((const uint4*)x2)[xidx];
        float4 o0, o1;
        o0.x = 0.8f * bflo(u1.x) + 0.15f * bflo(u2.x) + di * A.a0;
        o0.y = 0.8f * bfhi(u1.x) + 0.15f * bfhi(u2.x) + di * A.a1;
        o0.z = 0.8f * bflo(u1.y) + 0.15f * bflo(u2.y) + di * A.a2;
        o0.w = 0.8f * bfhi(u1.y) + 0.15f * bfhi(u2.y) + di * A.a3;
        o1.x = 0.8f * bflo(u1.z) + 0.15f * bflo(u2.z) + di * A.a4;
        o1.y = 0.8f * bfhi(u1.z) + 0.15f * bfhi(u2.z) + di * A.a5;
        o1.z = 0.8f * bflo(u1.w) + 0.15f * bflo(u2.w) + di * A.a6;
        o1.w = 0.8f * bfhi(u1.w) + 0.15f * bfhi(u2.w) + di * A.a7;
        float4* h4 = (float4*)h;
        size_t hbase = (size_t)i * 16 + (size_t)(half * 4 + c4) * 2;
        h4[hbase] = o0;
        h4[hbase + 1] = o1;
    }
}

// ---------------- launch ----------------

extern "C" void kernel_launch(void* const* d_in, const int* in_sizes, int n_in,
                              void* d_out, int out_size, void* d_ws, size_t ws_size,
                              hipStream_t stream) {
    const float* feat = (const float*)d_in[0];
    const int*   src  = (const int*)d_in[1];
    const int*   dst  = (const int*)d_in[2];
    float* h = (float*)d_out;

    char* ws = (char*)d_ws;
    // layout (4B words), ~64.6 MB, no aliasing
    int*      offs     = (int*)(ws);                      // 50432
    float*    dinv     = (float*)(ws + 50432u  * 4);      // 50432
    int*      tot      = (int*)(ws + 100864u * 4);        // 50432
    int*      partials = (int*)(ws + 151296u * 4);        // 256
    int2*     csr2     = (int2*)(ws + 151552u * 4);       // 800000 int2 = 1.6M words
    int*      pdst     = (int*)(ws + 1751552u * 4);       // 3.2M
    int*      psrc     = (int*)(ws + 4951552u * 4);       // 3.2M
    int*      gbase    = (int*)(ws + 8151552u * 4);       // 3.2M
    unsigned* featbf   = (unsigned*)(ws + 11351552u * 4); // 1.6M
    unsigned* bufA     = (unsigned*)(ws + 12951552u * 4); // 1.6M
    unsigned* bufB     = (unsigned*)(ws + 14551552u * 4); // 1.6M

    const int nE = N_EDGES;
    const int nN = N_NODES;
    const int B = 256;

    // 1. hist (src+dst) + feat->bf16 convert, one grid
    dim3 histGrid(G_STR, RANGES, 3);
    hist_cv_kernel<<<histGrid, HB, 0, stream>>>(src, dst, psrc, pdst, feat, featbf, nE);

    // 2. scanA: totals + dinv + partials
    scanA_kernel<<<SCAN_NBLK, SCAN_B, 0, stream>>>(pdst, psrc, tot, partials, dinv, nN);

    // 3. scanC (scanB folded): offs + gbase
    scanC_kernel<<<SCAN_NBLK, SCAN_B, 0, stream>>>(tot, pdst, partials, offs, gbase, nN);

    // 4. scatter into fused (src, w) CSR
    dim3 scatGrid(G_STR, RANGES);
    scatter_lds_kernel<<<scatGrid, HB, 0, stream>>>(src, dst, gbase, dinv, csr2, nE);

    // 5-7. SpMM hops (2 waves/node feature-split); h written once in final hop
    const int spmmGrid = (nN * 128 + B - 1) / B;   // two waves per node
    spmm_mid_kernel<<<spmmGrid, B, 0, stream>>>(offs, csr2, dinv, featbf, bufA);
    spmm_mid_kernel<<<spmmGrid, B, 0, stream>>>(offs, csr2, dinv, bufA, bufB);
    spmm_final_kernel<<<spmmGrid, B, 0, stream>>>(offs, csr2, dinv, bufA, bufB, h);
}

// Round 18
// 183.973 us; speedup vs baseline: 1.3023x; 1.3023x over previous
//
#include <hip/hip_runtime.h>
#include <hip/hip_bf16.h>

#define N_NODES 50000
#define N_EDGES 800000
#define D_FEAT  64
#define SCAN_B  256
#define SCAN_NBLK ((N_NODES + SCAN_B - 1) / SCAN_B)   // 196
#define NB      12800    // LDS bins per range (50 KB)
#define RANGES  4        // ceil(50000/12800)
#define G_STR   64       // edge stripes
#define NPP     50000
#define HB      512      // hist/scatter block size (8 waves)

// ---------------- bf16 helpers ----------------
__device__ __forceinline__ float bflo(unsigned u) { return __uint_as_float(u << 16); }
__device__ __forceinline__ float bfhi(unsigned u) { return __uint_as_float(u & 0xFFFF0000u); }
__device__ __forceinline__ unsigned pack_bf16(float a, float b) {
    __hip_bfloat16 x = __float2bfloat16(a), y = __float2bfloat16(b);
    unsigned short ux = *reinterpret_cast<unsigned short*>(&x);
    unsigned short uy = *reinterpret_cast<unsigned short*>(&y);
    return (unsigned)ux | ((unsigned)uy << 16);
}

// ---------------- build kernels (no global atomics) ----------------

// grid (G_STR, RANGES, 3). z=0: src hist; z=1: dst hist; z=2: feat->bf16 convert.
// Edge keys loaded as int4 (4 edges per thread-iteration, coalesced).
__global__ void hist_cv_kernel(const int* __restrict__ src, const int* __restrict__ dst,
                               int* __restrict__ psrc, int* __restrict__ pdst,
                               const float* __restrict__ feat, unsigned* __restrict__ featbf,
                               int nE) {
    int type = blockIdx.z;
    int t = threadIdx.x;
    if (type == 2) {
        int cb = blockIdx.x * RANGES + blockIdx.y;   // 0..255
        const float4* f4 = (const float4*)feat;
        for (int i = cb * HB + t; i < N_NODES * 16; i += 256 * HB) {
            float4 v = f4[i];
            featbf[2 * i]     = pack_bf16(v.x, v.y);
            featbf[2 * i + 1] = pack_bf16(v.z, v.w);
        }
        return;
    }
    __shared__ int bins[NB];
    for (int i = t; i < NB; i += HB) bins[i] = 0;
    __syncthreads();
    int g = blockIdx.x, range = blockIdx.y;
    const int4* keys4 = (const int4*)((type == 0) ? src : dst);
    int lo = range * NB;
    int nE4 = nE >> 2;   // 200000
    for (int e = g * HB + t; e < nE4; e += G_STR * HB) {
        int4 kv = keys4[e];
        unsigned k0 = (unsigned)(kv.x - lo); if (k0 < NB) atomicAdd(&bins[k0], 1);
        unsigned k1 = (unsigned)(kv.y - lo); if (k1 < NB) atomicAdd(&bins[k1], 1);
        unsigned k2 = (unsigned)(kv.z - lo); if (k2 < NB) atomicAdd(&bins[k2], 1);
        unsigned k3 = (unsigned)(kv.w - lo); if (k3 < NB) atomicAdd(&bins[k3], 1);
    }
    __syncthreads();
    int* p = ((type == 0) ? psrc : pdst) + g * NPP;
    for (int i = t; i < NB; i += HB) {
        int node = lo + i;
        if (node < N_NODES) p[node] = bins[i];
    }
}

// Phase A: per-node totals -> tot; block sums -> partials; fused dinv
__global__ void scanA_kernel(const int* __restrict__ pdst, const int* __restrict__ psrc,
                             int* __restrict__ tot, int* __restrict__ partials,
                             float* __restrict__ dinv, int n) {
    __shared__ int red[SCAN_B];
    int t = threadIdx.x;
    int idx = blockIdx.x * SCAN_B + t;
    int v = 0;
    if (idx < n) {
        int cs = 0;
        #pragma unroll 16
        for (int g = 0; g < G_STR; g++) {
            v  += pdst[g * NPP + idx];
            cs += psrc[g * NPP + idx];
        }
        tot[idx] = v;
        dinv[idx] = (cs > 0) ? rsqrtf((float)cs) : 0.0f;
    }
    red[t] = v;
    __syncthreads();
    for (int off = SCAN_B / 2; off > 0; off >>= 1) {
        if (t < off) red[t] += red[t + off];
        __syncthreads();
    }
    if (t == 0) partials[blockIdx.x] = red[0];
}

// Phase C (scanB folded in): every block scans the 196 partials in LDS for its
// own base, then does the per-node exclusive scan -> offs and gbase.
__global__ void scanC_kernel(const int* __restrict__ tot, const int* __restrict__ pdst,
                             const int* __restrict__ partials,
                             int* __restrict__ offs, int* __restrict__ gbase, int n) {
    __shared__ int sp[SCAN_B];
    __shared__ int sn[SCAN_B];
    int t = threadIdx.x;
    int b = blockIdx.x;
    sp[t] = (t < SCAN_NBLK) ? partials[t] : 0;
    __syncthreads();
    for (int off = 1; off < SCAN_B; off <<= 1) {
        int u = (t >= off) ? sp[t - off] : 0;
        __syncthreads();
        sp[t] += u;
        __syncthreads();
    }
    int base = (b == 0) ? 0 : sp[b - 1];
    if (b == SCAN_NBLK - 1 && t == 0) offs[n] = sp[SCAN_NBLK - 1];
    int idx = b * SCAN_B + t;
    int v = (idx < n) ? tot[idx] : 0;
    sn[t] = v;
    __syncthreads();
    for (int off = 1; off < SCAN_B; off <<= 1) {
        int u = (t >= off) ? sn[t - off] : 0;
        __syncthreads();
        sn[t] += u;
        __syncthreads();
    }
    if (idx < n) {
        int off0 = base + sn[t] - v;   // exclusive
        offs[idx] = off0;
        int run = off0;
        #pragma unroll 16
        for (int g = 0; g < G_STR; g++) {
            gbase[g * NPP + idx] = run;
            run += pdst[g * NPP + idx];
        }
    }
}

// grid (G_STR, RANGES). Writes fused (src, dinv[src]) entries via LDS cursors.
// Edge keys loaded as int4 (4 edges per thread-iteration).
__global__ void scatter_lds_kernel(const int* __restrict__ src, const int* __restrict__ dst,
                                   const int* __restrict__ gbase, const float* __restrict__ dinv,
                                   int2* __restrict__ csr2, int nE) {
    __shared__ int cur[NB];
    int t = threadIdx.x;
    int g = blockIdx.x, range = blockIdx.y;
    int lo = range * NB;
    for (int i = t; i < NB; i += HB) {
        int node = lo + i;
        cur[i] = (node < N_NODES) ? gbase[g * NPP + node] : 0;
    }
    __syncthreads();
    const int4* src4 = (const int4*)src;
    const int4* dst4 = (const int4*)dst;
    int nE4 = nE >> 2;
    for (int e = g * HB + t; e < nE4; e += G_STR * HB) {
        int4 dv = dst4[e];
        int4 sv = src4[e];
        unsigned k0 = (unsigned)(dv.x - lo);
        if (k0 < NB) { int pos = atomicAdd(&cur[k0], 1); csr2[pos] = make_int2(sv.x, __float_as_int(dinv[sv.x])); }
        unsigned k1 = (unsigned)(dv.y - lo);
        if (k1 < NB) { int pos = atomicAdd(&cur[k1], 1); csr2[pos] = make_int2(sv.y, __float_as_int(dinv[sv.y])); }
        unsigned k2 = (unsigned)(dv.z - lo);
        if (k2 < NB) { int pos = atomicAdd(&cur[k2], 1); csr2[pos] = make_int2(sv.z, __float_as_int(dinv[sv.z])); }
        unsigned k3 = (unsigned)(dv.w - lo);
        if (k3 < NB) { int pos = atomicAdd(&cur[k3], 1); csr2[pos] = make_int2(sv.w, __float_as_int(dinv[sv.w])); }
    }
}

// ---------------- gather SpMM (bf16 x, f32 accumulate) ----------------
// One wave per dst node. eg = lane>>3 (edge slot 0..7), c8 = lane&7 (16B col
// group). 16 edges in flight; shfl_xor 8/16/32 reduction; lanes 0..7 write.

struct Acc8 { float a0, a1, a2, a3, a4, a5, a6, a7; };

__device__ __forceinline__ Acc8 spmm_gather(int i, const int* __restrict__ offs,
                                            const int2* __restrict__ csr2,
                                            const unsigned* __restrict__ x,
                                            int eg, int c8) {
    int bg = offs[i], e2 = offs[i + 1];
    const uint4* x4 = (const uint4*)x;
    float a0 = 0, a1 = 0, a2 = 0, a3 = 0, a4 = 0, a5 = 0, a6 = 0, a7 = 0;
    for (int j = bg; j < e2; j += 16) {
        int ej0 = j + eg, ej1 = j + 8 + eg;
        bool v0 = ej0 < e2, v1 = ej1 < e2;
        int2 sw0 = csr2[v0 ? ej0 : (e2 - 1)];
        int2 sw1 = csr2[v1 ? ej1 : (e2 - 1)];
        float w0 = v0 ? __int_as_float(sw0.y) : 0.0f;
        float w1 = v1 ? __int_as_float(sw1.y) : 0.0f;
        uint4 r0 = x4[(size_t)sw0.x * 8 + c8];
        uint4 r1 = x4[(size_t)sw1.x * 8 + c8];
        a0 += w0 * bflo(r0.x) + w1 * bflo(r1.x);
        a1 += w0 * bfhi(r0.x) + w1 * bfhi(r1.x);
        a2 += w0 * bflo(r0.y) + w1 * bflo(r1.y);
        a3 += w0 * bfhi(r0.y) + w1 * bfhi(r1.y);
        a4 += w0 * bflo(r0.z) + w1 * bflo(r1.z);
        a5 += w0 * bfhi(r0.z) + w1 * bfhi(r1.z);
        a6 += w0 * bflo(r0.w) + w1 * bflo(r1.w);
        a7 += w0 * bfhi(r0.w) + w1 * bfhi(r1.w);
    }
    #pragma unroll
    for (int d = 8; d <= 32; d <<= 1) {
        a0 += __shfl_xor(a0, d); a1 += __shfl_xor(a1, d);
        a2 += __shfl_xor(a2, d); a3 += __shfl_xor(a3, d);
        a4 += __shfl_xor(a4, d); a5 += __shfl_xor(a5, d);
        a6 += __shfl_xor(a6, d); a7 += __shfl_xor(a7, d);
    }
    Acc8 r = {a0, a1, a2, a3, a4, a5, a6, a7};
    return r;
}

// mid hop: y = A @ x  (bf16 out only, no h traffic)
__global__ void spmm_mid_kernel(const int* __restrict__ offs, const int2* __restrict__ csr2,
                                const float* __restrict__ dinv,
                                const unsigned* __restrict__ x, unsigned* __restrict__ y) {
    int i = (blockIdx.x * blockDim.x + threadIdx.x) >> 6;
    if (i >= N_NODES) return;
    int lane = threadIdx.x & 63;
    Acc8 A = spmm_gather(i, offs, csr2, x, lane >> 3, lane & 7);
    if (lane < 8) {
        int c8 = lane & 7;
        float di = dinv[i];
        uint4 p;
        p.x = pack_bf16(A.a0 * di, A.a1 * di);
        p.y = pack_bf16(A.a2 * di, A.a3 * di);
        p.z = pack_bf16(A.a4 * di, A.a5 * di);
        p.w = pack_bf16(A.a6 * di, A.a7 * di);
        ((uint4*)y)[(size_t)i * 8 + c8] = p;
    }
}

// final hop: x3 = A @ x2 ; h = 0.8*x1 + 0.15*x2 + 0.05*x3 (single h write)
__global__ void spmm_final_kernel(const int* __restrict__ offs, const int2* __restrict__ csr2,
                                  const float* __restrict__ dinv,
                                  const unsigned* __restrict__ x1, const unsigned* __restrict__ x2,
                                  float* __restrict__ h) {
    int i = (blockIdx.x * blockDim.x + threadIdx.x) >> 6;
    if (i >= N_NODES) return;
    int lane = threadIdx.x & 63;
    Acc8 A = spmm_gather(i, offs, csr2, x2, lane >> 3, lane & 7);
    if (lane < 8) {
        int c8 = lane & 7;
        float di = dinv[i] * 0.05f;
        uint4 u1 = ((const uint4*)x1)[(size_t)i * 8 + c8];
        uint4 u2 = ((const uint4*)x2)[(size_t)i * 8 + c8];
        float4 o0, o1;
        o0.x = 0.8f * bflo(u1.x) + 0.15f * bflo(u2.x) + di * A.a0;
        o0.y = 0.8f * bfhi(u1.x) + 0.15f * bfhi(u2.x) + di * A.a1;
        o0.z = 0.8f * bflo(u1.y) + 0.15f * bflo(u2.y) + di * A.a2;
        o0.w = 0.8f * bfhi(u1.y) + 0.15f * bfhi(u2.y) + di * A.a3;
        o1.x = 0.8f * bflo(u1.z) + 0.15f * bflo(u2.z) + di * A.a4;
        o1.y = 0.8f * bfhi(u1.z) + 0.15f * bfhi(u2.z) + di * A.a5;
        o1.z = 0.8f * bflo(u1.w) + 0.15f * bflo(u2.w) + di * A.a6;
        o1.w = 0.8f * bfhi(u1.w) + 0.15f * bfhi(u2.w) + di * A.a7;
        float4* h4 = (float4*)h;
        size_t hbase = (size_t)i * 16 + (size_t)c8 * 2;
        h4[hbase] = o0;
        h4[hbase + 1] = o1;
    }
}

// ---------------- launch ----------------

extern "C" void kernel_launch(void* const* d_in, const int* in_sizes, int n_in,
                              void* d_out, int out_size, void* d_ws, size_t ws_size,
                              hipStream_t stream) {
    const float* feat = (const float*)d_in[0];
    const int*   src  = (const int*)d_in[1];
    const int*   dst  = (const int*)d_in[2];
    float* h = (float*)d_out;

    char* ws = (char*)d_ws;
    // layout (4B words), ~64.6 MB, no aliasing
    int*      offs     = (int*)(ws);                      // 50432
    float*    dinv     = (float*)(ws + 50432u  * 4);      // 50432
    int*      tot      = (int*)(ws + 100864u * 4);        // 50432
    int*      partials = (int*)(ws + 151296u * 4);        // 256
    int2*     csr2     = (int2*)(ws + 151552u * 4);       // 800000 int2 = 1.6M words
    int*      pdst     = (int*)(ws + 1751552u * 4);       // 3.2M
    int*      psrc     = (int*)(ws + 4951552u * 4);       // 3.2M
    int*      gbase    = (int*)(ws + 8151552u * 4);       // 3.2M
    unsigned* featbf   = (unsigned*)(ws + 11351552u * 4); // 1.6M
    unsigned* bufA     = (unsigned*)(ws + 12951552u * 4); // 1.6M
    unsigned* bufB     = (unsigned*)(ws + 14551552u * 4); // 1.6M

    const int nE = N_EDGES;
    const int nN = N_NODES;
    const int B = 256;

    // 1. hist (src+dst) + feat->bf16 convert, one grid
    dim3 histGrid(G_STR, RANGES, 3);
    hist_cv_kernel<<<histGrid, HB, 0, stream>>>(src, dst, psrc, pdst, feat, featbf, nE);

    // 2. scanA: totals + dinv + partials
    scanA_kernel<<<SCAN_NBLK, SCAN_B, 0, stream>>>(pdst, psrc, tot, partials, dinv, nN);

    // 3. scanC (scanB folded): offs + gbase
    scanC_kernel<<<SCAN_NBLK, SCAN_B, 0, stream>>>(tot, pdst, partials, offs, gbase, nN);

    // 4. scatter into fused (src, w) CSR
    dim3 scatGrid(G_STR, RANGES);
    scatter_lds_kernel<<<scatGrid, HB, 0, stream>>>(src, dst, gbase, dinv, csr2, nE);

    // 5-7. SpMM hops (1 wave/node, 16 edges in flight); h written once at the end
    const int spmmGrid = (nN * 64 + B - 1) / B;
    spmm_mid_kernel<<<spmmGrid, B, 0, stream>>>(offs, csr2, dinv, featbf, bufA);
    spmm_mid_kernel<<<spmmGrid, B, 0, stream>>>(offs, csr2, dinv, bufA, bufB);
    spmm_final_kernel<<<spmmGrid, B, 0, stream>>>(offs, csr2, dinv, bufA, bufB, h);
}